// Round 10
// baseline (360.739 us; speedup 1.0000x reference)
//
#include <hip/hip_runtime.h>

#define NNODE 50000
#define NEDGE 800000
#define DIM   128
#define NEG   0.2f
#define NBUCK 196
#define EPB1  2048
#define NB1   391
#define GBLK  391          // ceil(NNODE/128) for 512-thread mfma_k
#define GN    12500        // ceil(NNODE/4) node-blocks (4 waves of 1 node)
#define SB_PA (NB1)        // setup_k block ranges
#define SB_PH (SB_PA + 32)
#define SB_MV (SB_PH + 65) // prepH: 64 compute blocks + 1 bf3 block
#define SB_CV (SB_MV + 193)
#define SB_TOT (SB_CV + GN)
#define SCX   (NBUCK + 1 + GN)  // scanx_k: 196 scans + gbase + 12500 dual

typedef __attribute__((ext_vector_type(8))) short bf16x8;
typedef __attribute__((ext_vector_type(4))) float f32x4;

__device__ __forceinline__ float wmax(float v){
  #pragma unroll
  for (int m = 32; m > 0; m >>= 1) v = fmaxf(v, __shfl_xor(v, m));
  return v;
}
__device__ __forceinline__ float wsum(float v){
  #pragma unroll
  for (int m = 32; m > 0; m >>= 1) v += __shfl_xor(v, m);
  return v;
}
__device__ __forceinline__ int wsumi(int v){
  #pragma unroll
  for (int m = 32; m > 0; m >>= 1) v += __shfl_xor(v, m);
  return v;
}
__device__ __forceinline__ unsigned short f2bf(float f){
  unsigned int x = __float_as_uint(f);
  return (unsigned short)((x + 0x7fffu + ((x >> 16) & 1u)) >> 16);
}
__device__ __forceinline__ float bflo(unsigned u){ return __uint_as_float(u << 16); }
__device__ __forceinline__ float bfhi(unsigned u){ return __uint_as_float(u & 0xffff0000u); }

// ---- setup_k: bhist2 | prepA | prepH | mv6 | cvt (independent, one launch) ----
__global__ __launch_bounds__(256) void setup_k(
    const int* __restrict__ ei,
    const float* __restrict__ x,
    const float* __restrict__ w0s, const float* __restrict__ a0s,
    const float* __restrict__ w0d, const float* __restrict__ a0d,
    const float* __restrict__ bc0, const float* __restrict__ wl0,
    const float* __restrict__ bl0,
    const float* __restrict__ w1,  const float* __restrict__ a1s,
    const float* __restrict__ a1d, const float* __restrict__ bc1,
    const float* __restrict__ wl1, const float* __restrict__ bl1,
    const float* __restrict__ w2,  const float* __restrict__ a2s,
    const float* __restrict__ a2d, const float* __restrict__ bc2,
    const float* __restrict__ wl2, const float* __restrict__ bl2,
    const float* __restrict__ wh,  const float* __restrict__ bh,
    int* __restrict__ cnt,
    unsigned short* __restrict__ Wz1, unsigned short* __restrict__ Wz2,
    unsigned short* __restrict__ Wz3, float* __restrict__ bf3,
    float* __restrict__ uv, float* __restrict__ bf1, float* __restrict__ bf2,
    unsigned int* __restrict__ Xb){
  int bid = blockIdx.x;

  if (bid < NB1){                       // ---- bhist2 ----
    __shared__ int h[NBUCK];
    const int* dst = ei + NEDGE;
    for (int i = threadIdx.x; i < NBUCK; i += 256) h[i] = 0;
    __syncthreads();
    int e0 = bid * EPB1 + threadIdx.x;
    #pragma unroll
    for (int i = 0; i < 8; ++i){
      int e = e0 + i * 256;
      if (e < NEDGE) atomicAdd(&h[dst[e] >> 8], 1);
    }
    __syncthreads();
    for (int i = threadIdx.x; i < NBUCK; i += 256)
      cnt[i * NB1 + bid] = h[i];
    return;
  }
  if (bid < SB_PH){                     // ---- prepA ----
    int g = (bid - SB_PA) * 256 + threadIdx.x;   // 0..8191
    int layer = g >> 12;
    int rem = g & 4095;
    int ct = rem >> 9, q = (rem >> 6) & 7, lane = rem & 63;
    int quad = lane >> 4;
    int c = ct * 16 + (lane & 15);
    const float* wA = layer ? w1 : w0s;
    const float* wB = layer ? wl1 : wl0;
    unsigned short* dst = (layer ? Wz2 : Wz1) + ((size_t)(ct * 8 + q) * 64 + lane) * 8;
    #pragma unroll
    for (int j = 0; j < 8; ++j){
      int k = q * 32 + quad * 8 + j;
      float v = (k < 128) ? wA[k * 128 + c] : wB[(k - 128) * 128 + c];
      dst[j] = f2bf(v);
    }
    return;
  }
  if (bid < SB_MV){                     // ---- prepH: one output per thread ----
    int pb = bid - SB_PH;
    if (pb == 64){
      int c = threadIdx.x;
      if (c < 64){
        float s = bh[c];
        for (int t = 0; t < 128; ++t) s += (bc2[t] + bl2[t]) * wh[t * 64 + c];
        bf3[c] = s;
      }
      return;
    }
    int g = pb * 256 + threadIdx.x;     // 0..16383
    int k = g >> 6, c = g & 63;
    const float* src = (k < 128) ? (w2 + k * 128) : (wl2 + (k - 128) * 128);
    float s = 0.f;
    for (int t = 0; t < 128; ++t) s += src[t] * wh[t * 64 + c];
    int ct = c >> 4, q = k >> 5, quad = (k >> 3) & 3, j = k & 7;
    int ln = quad * 16 + (c & 15);
    Wz3[((size_t)(ct * 8 + q) * 64 + ln) * 8 + j] = f2bf(s);
    return;
  }
  if (bid < SB_CV){                     // ---- mv6 + fused biases ----
    int mb = bid - SB_MV;
    if (mb == 192){
      int t = threadIdx.x;
      if (t < 128) bf1[t] = bc0[t] + bl0[t];
      else bf2[t - 128] = bc1[t - 128] + bl1[t - 128];
      return;
    }
    int lane = threadIdx.x & 63;
    int idx = mb * 4 + (threadIdx.x >> 6);   // 0..767
    int grp = idx >> 7, r = idx & 127;
    const float* W; const float* a;
    switch (grp){
      case 0: W = w0s; a = a0s; break;
      case 1: W = w0d; a = a0d; break;
      case 2: W = w1;  a = a1s; break;
      case 3: W = w1;  a = a1d; break;
      case 4: W = w2;  a = a2s; break;
      default: W = w2; a = a2d; break;
    }
    float2 w = ((const float2*)(W + r * DIM))[lane];
    float2 av = ((const float2*)a)[lane];
    float s = wsum(w.x * av.x + w.y * av.y);
    if (lane == 0) uv[grp * 128 + r] = s;
    return;
  }
  {                                     // ---- cvt: x -> bf16 row-major ----
    int lane = threadIdx.x & 63;
    int n = (bid - SB_CV) * 4 + (threadIdx.x >> 6);
    if (n >= NNODE) return;
    float2 xv = ((const float2*)(x + (size_t)n * DIM))[lane];
    Xb[(size_t)n * 64 + lane] = (unsigned)f2bf(xv.x) | ((unsigned)f2bf(xv.y) << 16);
  }
}

// ---- scanx_k: per-bucket row scans | gbase (parallel, coalesced) | dual ----
// gbase block: one bucket per WAVE (lane-coalesced 391-sum + shuffle reduce)
// instead of r9's one-bucket-per-thread serial loops -- kills the ~8us
// single-block tail that ate the r9 merge's gain.
__global__ __launch_bounds__(256) void scanx_k(const int* __restrict__ cnt,
                                               int* __restrict__ cbase,
                                               int* __restrict__ gbase,
                                               int* __restrict__ rp,
                                               const float* __restrict__ X,
                                               const float* __restrict__ uv,
                                               float* __restrict__ als,
                                               float* __restrict__ ald){
  int bid = blockIdx.x, t = threadIdx.x;
  if (bid < NBUCK){                     // ---- row scan for bucket bid ----
    __shared__ int sd[256];
    const int* row = cnt + (size_t)bid * NB1;
    int i0 = t * 2, i1 = t * 2 + 1;
    int v0 = (i0 < NB1) ? row[i0] : 0;
    int v1 = (i1 < NB1) ? row[i1] : 0;
    int s = v0 + v1;
    sd[t] = s; __syncthreads();
    #pragma unroll
    for (int off = 1; off < 256; off <<= 1){
      int u = (t >= off) ? sd[t - off] : 0;
      __syncthreads();
      sd[t] += u;
      __syncthreads();
    }
    int ex = sd[t] - s;
    if (i0 < NB1) cbase[(size_t)bid * NB1 + i0] = ex;
    if (i1 < NB1) cbase[(size_t)bid * NB1 + i1] = ex + v0;
    return;
  }
  if (bid == NBUCK){                    // ---- gbase: totals + scan ----
    __shared__ int bt[NBUCK];
    __shared__ int sd[256];
    int w = t >> 6, lane = t & 63;
    for (int bkt = w; bkt < NBUCK; bkt += 4){
      const int* row = cnt + (size_t)bkt * NB1;
      int sum = 0;
      for (int j = lane; j < NB1; j += 64) sum += row[j];
      sum = wsumi(sum);
      if (lane == 0) bt[bkt] = sum;
    }
    __syncthreads();
    int v = (t < NBUCK) ? bt[t] : 0;
    sd[t] = v; __syncthreads();
    #pragma unroll
    for (int off = 1; off < 256; off <<= 1){
      int u = (t >= off) ? sd[t - off] : 0;
      __syncthreads();
      sd[t] += u;
      __syncthreads();
    }
    if (t < NBUCK) gbase[t] = sd[t] - v;
    if (t == NBUCK - 1) gbase[NBUCK] = sd[t];
    if (t == 0) rp[NNODE] = NEDGE;
    return;
  }
  {                                     // ---- layer-0 logits: x@u, x@v ----
    int lane = t & 63;
    int n = (bid - NBUCK - 1) * 4 + (t >> 6);
    if (n >= NNODE) return;
    float2 xv = ((const float2*)(X + (size_t)n * DIM))[lane];
    float2 uu = ((const float2*)uv)[lane];
    float2 vv = ((const float2*)(uv + 128))[lane];
    float s1 = wsum(xv.x * uu.x + xv.y * uu.y);
    float s2 = wsum(xv.x * vv.x + xv.y * vv.y);
    if (lane == 0){ als[n] = s1; ald[n] = s2; }
  }
}

__global__ __launch_bounds__(256) void scat2_k(const int* __restrict__ ei,
                                               const int* __restrict__ gbase,
                                               const int* __restrict__ cbase,
                                               unsigned int* __restrict__ packed){
  __shared__ int lcur[NBUCK];
  for (int i = threadIdx.x; i < NBUCK; i += 256) lcur[i] = 0;
  __syncthreads();
  int e0 = blockIdx.x * EPB1 + threadIdx.x;
  #pragma unroll
  for (int i = 0; i < 8; ++i){
    int e = e0 + i * 256;
    if (e < NEDGE){
      int s = ei[e], d = ei[NEDGE + e];
      int b = d >> 8;
      int r = atomicAdd(&lcur[b], 1);
      int pos = gbase[b] + cbase[(size_t)b * NB1 + blockIdx.x] + r;
      packed[pos] = ((unsigned)d << 16) | (unsigned)s;
    }
  }
}

// 512 threads: 196 blocks were only 784 waves on 1024 SIMDs at 256 thr --
// latency-exposed. 512 doubles resident waves and halves per-thread rounds.
__global__ __launch_bounds__(512) void build_k(const int* __restrict__ gbase,
                                               const unsigned int* __restrict__ packed,
                                               int* __restrict__ rp,
                                               unsigned short* __restrict__ es){
  __shared__ int h[256], sd[256], cur[256];
  int b = blockIdx.x, t = threadIdx.x;
  int s0 = gbase[b], s1 = gbase[b + 1];
  if (t < 256) h[t] = 0;
  __syncthreads();
  for (int i = s0 + t; i < s1; i += 512)
    atomicAdd(&h[(packed[i] >> 16) & 255], 1);
  __syncthreads();
  int v = (t < 256) ? h[t] : 0;
  if (t < 256) sd[t] = v;
  __syncthreads();
  #pragma unroll
  for (int off = 1; off < 256; off <<= 1){
    int u = (t >= off && t < 256) ? sd[t - off] : 0;
    __syncthreads();
    if (t < 256) sd[t] += u;
    __syncthreads();
  }
  if (t < 256){
    int ex = sd[t] - v;
    cur[t] = ex;
    int d = b * 256 + t;
    if (d < NNODE) rp[d] = s0 + ex;
  }
  __syncthreads();
  for (int i = s0 + t; i < s1; i += 512){
    unsigned int p = packed[i];
    int ld = (p >> 16) & 255;
    int pos = atomicAdd(&cur[ld], 1);
    es[s0 + pos] = (unsigned short)(p & 0xffffu);
  }
}

// ---------------- GAT: Mb[n] = softmax-weighted sum of Hg rows (bf16) ----------------
// als[s] gather issued immediately after es (before the row loads) so the
// softmax dependency chain starts as early as possible.
__global__ __launch_bounds__(256) void gat_k(const int* __restrict__ rp,
                                             const unsigned short* __restrict__ es,
                                             const float* __restrict__ als,
                                             const float* __restrict__ ald,
                                             const unsigned int* __restrict__ A,
                                             unsigned int* __restrict__ Mb){
  int lane = threadIdx.x & 63;
  int n = blockIdx.x * 4 + (threadIdx.x >> 6);
  if (n >= NNODE) return;
  int start = rp[n], end = rp[n + 1];
  int deg = end - start;
  float ad = ald[n];
  int half = lane >> 4, sub = lane & 15;
  const uint4* A4 = (const uint4*)A;

  if (deg <= 32){
    int s = (lane < deg) ? (int)es[start + lane] : 0;
    float alv = (lane < deg) ? als[s] : 0.f;   // issue scattered 4B load early

    int s0 = __shfl(s, half),      s1 = __shfl(s, 4 + half);
    int s2 = __shfl(s, 8 + half),  s3 = __shfl(s, 12 + half);
    uint4 p0 = A4[(size_t)s0 * 16 + sub];
    uint4 p1 = A4[(size_t)s1 * 16 + sub];
    uint4 p2 = A4[(size_t)s2 * 16 + sub];
    uint4 p3 = A4[(size_t)s3 * 16 + sub];
    uint4 p4, p5, p6, p7;
    bool big = deg > 16;
    if (big){
      int s4 = __shfl(s, 16 + half), s5 = __shfl(s, 20 + half);
      int s6 = __shfl(s, 24 + half), s7 = __shfl(s, 28 + half);
      p4 = A4[(size_t)s4 * 16 + sub];
      p5 = A4[(size_t)s5 * 16 + sub];
      p6 = A4[(size_t)s6 * 16 + sub];
      p7 = A4[(size_t)s7 * 16 + sub];
    }

    float z = -3.0e38f;
    if (lane < deg){
      float t = alv + ad;
      z = t > 0.f ? t : NEG * t;
    }
    float m = wmax(z);
    float e = (lane < deg) ? __expf(z - m) : 0.f;
    float denom = wsum(e);
    float rinv = (deg > 0) ? 1.f / denom : 0.f;

    float w0 = __shfl(e, half),      w1 = __shfl(e, 4 + half);
    float w2 = __shfl(e, 8 + half),  w3 = __shfl(e, 12 + half);
    float a0=0.f,a1=0.f,a2=0.f,a3=0.f,a4=0.f,a5=0.f,a6=0.f,a7=0.f;
    a0 = fmaf(w0, bflo(p0.x), a0); a1 = fmaf(w0, bfhi(p0.x), a1);
    a2 = fmaf(w0, bflo(p0.y), a2); a3 = fmaf(w0, bfhi(p0.y), a3);
    a4 = fmaf(w0, bflo(p0.z), a4); a5 = fmaf(w0, bfhi(p0.z), a5);
    a6 = fmaf(w0, bflo(p0.w), a6); a7 = fmaf(w0, bfhi(p0.w), a7);
    a0 = fmaf(w1, bflo(p1.x), a0); a1 = fmaf(w1, bfhi(p1.x), a1);
    a2 = fmaf(w1, bflo(p1.y), a2); a3 = fmaf(w1, bfhi(p1.y), a3);
    a4 = fmaf(w1, bflo(p1.z), a4); a5 = fmaf(w1, bfhi(p1.z), a5);
    a6 = fmaf(w1, bflo(p1.w), a6); a7 = fmaf(w1, bfhi(p1.w), a7);
    a0 = fmaf(w2, bflo(p2.x), a0); a1 = fmaf(w2, bfhi(p2.x), a1);
    a2 = fmaf(w2, bflo(p2.y), a2); a3 = fmaf(w2, bfhi(p2.y), a3);
    a4 = fmaf(w2, bflo(p2.z), a4); a5 = fmaf(w2, bfhi(p2.z), a5);
    a6 = fmaf(w2, bflo(p2.w), a6); a7 = fmaf(w2, bfhi(p2.w), a7);
    a0 = fmaf(w3, bflo(p3.x), a0); a1 = fmaf(w3, bfhi(p3.x), a1);
    a2 = fmaf(w3, bflo(p3.y), a2); a3 = fmaf(w3, bfhi(p3.y), a3);
    a4 = fmaf(w3, bflo(p3.z), a4); a5 = fmaf(w3, bfhi(p3.z), a5);
    a6 = fmaf(w3, bflo(p3.w), a6); a7 = fmaf(w3, bfhi(p3.w), a7);
    if (big){
      float w4 = __shfl(e, 16 + half), w5 = __shfl(e, 20 + half);
      float w6 = __shfl(e, 24 + half), w7 = __shfl(e, 28 + half);
      a0 = fmaf(w4, bflo(p4.x), a0); a1 = fmaf(w4, bfhi(p4.x), a1);
      a2 = fmaf(w4, bflo(p4.y), a2); a3 = fmaf(w4, bfhi(p4.y), a3);
      a4 = fmaf(w4, bflo(p4.z), a4); a5 = fmaf(w4, bfhi(p4.z), a5);
      a6 = fmaf(w4, bflo(p4.w), a6); a7 = fmaf(w4, bfhi(p4.w), a7);
      a0 = fmaf(w5, bflo(p5.x), a0); a1 = fmaf(w5, bfhi(p5.x), a1);
      a2 = fmaf(w5, bflo(p5.y), a2); a3 = fmaf(w5, bfhi(p5.y), a3);
      a4 = fmaf(w5, bflo(p5.z), a4); a5 = fmaf(w5, bfhi(p5.z), a5);
      a6 = fmaf(w5, bflo(p5.w), a6); a7 = fmaf(w5, bfhi(p5.w), a7);
      a0 = fmaf(w6, bflo(p6.x), a0); a1 = fmaf(w6, bfhi(p6.x), a1);
      a2 = fmaf(w6, bflo(p6.y), a2); a3 = fmaf(w6, bfhi(p6.y), a3);
      a4 = fmaf(w6, bflo(p6.z), a4); a5 = fmaf(w6, bfhi(p6.z), a5);
      a6 = fmaf(w6, bflo(p6.w), a6); a7 = fmaf(w6, bfhi(p6.w), a7);
      a0 = fmaf(w7, bflo(p7.x), a0); a1 = fmaf(w7, bfhi(p7.x), a1);
      a2 = fmaf(w7, bflo(p7.y), a2); a3 = fmaf(w7, bfhi(p7.y), a3);
      a4 = fmaf(w7, bflo(p7.z), a4); a5 = fmaf(w7, bfhi(p7.z), a5);
      a6 = fmaf(w7, bflo(p7.w), a6); a7 = fmaf(w7, bfhi(p7.w), a7);
    }
    #define RED(vv) vv += __shfl_xor(vv, 16); vv += __shfl_xor(vv, 32);
    RED(a0) RED(a1) RED(a2) RED(a3) RED(a4) RED(a5) RED(a6) RED(a7)
    #undef RED
    if (half == 0){
      uint4 o;
      o.x = (unsigned)f2bf(a0 * rinv) | ((unsigned)f2bf(a1 * rinv) << 16);
      o.y = (unsigned)f2bf(a2 * rinv) | ((unsigned)f2bf(a3 * rinv) << 16);
      o.z = (unsigned)f2bf(a4 * rinv) | ((unsigned)f2bf(a5 * rinv) << 16);
      o.w = (unsigned)f2bf(a6 * rinv) | ((unsigned)f2bf(a7 * rinv) << 16);
      ((uint4*)(Mb + (size_t)n * 64))[sub] = o;
    }
    return;
  }

  if (deg <= 64){
    int s = 0; float z = -3.0e38f;
    if (lane < deg){
      s = es[start + lane];
      float t = als[s] + ad;
      z = t > 0.f ? t : NEG * t;
    }
    float m = wmax(z);
    float e = (lane < deg) ? __expf(z - m) : 0.f;
    float denom = wsum(e);
    float rinv = (deg > 0) ? 1.f / denom : 0.f;

    float a0=0.f,a1=0.f,a2=0.f,a3=0.f,a4=0.f,a5=0.f,a6=0.f,a7=0.f;
    int dq = (deg + 7) & ~7;
    for (int j = 0; j < dq; j += 8){
      int   sA = __shfl(s, j + half);
      int   sB = __shfl(s, j + 4 + half);
      float wA = __shfl(e, j + half);
      float wB = __shfl(e, j + 4 + half);
      uint4 pA = A4[(size_t)sA * 16 + sub];
      uint4 pB = A4[(size_t)sB * 16 + sub];
      a0 = fmaf(wA, bflo(pA.x), a0); a1 = fmaf(wA, bfhi(pA.x), a1);
      a2 = fmaf(wA, bflo(pA.y), a2); a3 = fmaf(wA, bfhi(pA.y), a3);
      a4 = fmaf(wA, bflo(pA.z), a4); a5 = fmaf(wA, bfhi(pA.z), a5);
      a6 = fmaf(wA, bflo(pA.w), a6); a7 = fmaf(wA, bfhi(pA.w), a7);
      a0 = fmaf(wB, bflo(pB.x), a0); a1 = fmaf(wB, bfhi(pB.x), a1);
      a2 = fmaf(wB, bflo(pB.y), a2); a3 = fmaf(wB, bfhi(pB.y), a3);
      a4 = fmaf(wB, bflo(pB.z), a4); a5 = fmaf(wB, bfhi(pB.z), a5);
      a6 = fmaf(wB, bflo(pB.w), a6); a7 = fmaf(wB, bfhi(pB.w), a7);
    }
    #define RED(vv) vv += __shfl_xor(vv, 16); vv += __shfl_xor(vv, 32);
    RED(a0) RED(a1) RED(a2) RED(a3) RED(a4) RED(a5) RED(a6) RED(a7)
    #undef RED
    if (half == 0){
      uint4 o;
      o.x = (unsigned)f2bf(a0 * rinv) | ((unsigned)f2bf(a1 * rinv) << 16);
      o.y = (unsigned)f2bf(a2 * rinv) | ((unsigned)f2bf(a3 * rinv) << 16);
      o.z = (unsigned)f2bf(a4 * rinv) | ((unsigned)f2bf(a5 * rinv) << 16);
      o.w = (unsigned)f2bf(a6 * rinv) | ((unsigned)f2bf(a7 * rinv) << 16);
      ((uint4*)(Mb + (size_t)n * 64))[sub] = o;
    }
  } else {
    float2 acc = make_float2(0.f, 0.f);
    float mloc = -3.0e38f;
    for (int i = start + lane; i < end; i += 64){
      int s = es[i];
      float zz = als[s] + ad;
      zz = zz > 0.f ? zz : NEG * zz;
      mloc = fmaxf(mloc, zz);
    }
    float m = wmax(mloc);
    float dloc = 0.f;
    for (int i = start + lane; i < end; i += 64){
      int s = es[i];
      float zz = als[s] + ad;
      zz = zz > 0.f ? zz : NEG * zz;
      dloc += __expf(zz - m);
    }
    float rinv = 1.f / wsum(dloc);
    for (int i = start; i < end; ++i){
      int s = es[i];
      float zz = als[s] + ad;
      zz = zz > 0.f ? zz : NEG * zz;
      float w = __expf(zz - m);
      unsigned p = A[(size_t)s * 64 + lane];
      acc.x = fmaf(w, bflo(p), acc.x);
      acc.y = fmaf(w, bfhi(p), acc.y);
    }
    Mb[(size_t)n * 64 + lane] =
        (unsigned)f2bf(acc.x * rinv) | ((unsigned)f2bf(acc.y * rinv) << 16);
  }
}

// ------- K=256 fused MFMA: out = [Mb | Hin] @ Wz + bias ------------------
// 512 threads (8 waves, 128 rows/block): 8 waves share each 32KB Wz half
// through L1 (sync at ct==4 keeps them in the same window).
template<int FINAL>
__global__ __launch_bounds__(512) void mfma_k(const unsigned int* __restrict__ Mb,
                                              const unsigned int* __restrict__ Hin,
                                              const unsigned short* __restrict__ Wz,
                                              const float* __restrict__ bias,
                                              const float* __restrict__ u,
                                              const float* __restrict__ v,
                                              unsigned short* __restrict__ Hout,
                                              float* __restrict__ outf,
                                              float* __restrict__ als,
                                              float* __restrict__ ald){
  int lane = threadIdx.x & 63;
  int wid  = threadIdx.x >> 6;          // 0..7
  int r0   = blockIdx.x * 128 + wid * 16;
  int quad = lane >> 4;
  int col  = lane & 15;

  int rA = r0 + col; if (rA > NNODE - 1) rA = NNODE - 1;
  const bf16x8* mrow = (const bf16x8*)(Mb + (size_t)rA * 64);
  const bf16x8* hrow = (const bf16x8*)(Hin + (size_t)rA * 64);
  bf16x8 a[8];
  #pragma unroll
  for (int q = 0; q < 4; ++q){
    a[q]     = mrow[q * 4 + quad];
    a[q + 4] = hrow[q * 4 + quad];
  }

  const bf16x8* wz = (const bf16x8*)Wz;
  int rowq = r0 + quad * 4;
  float alsp[4] = {0.f, 0.f, 0.f, 0.f};
  float aldp[4] = {0.f, 0.f, 0.f, 0.f};
  const int NCT = FINAL ? 4 : 8;

  #pragma unroll
  for (int ct = 0; ct < NCT; ++ct){
    if (!FINAL && ct == 4) __syncthreads();   // keep waves in same 32KB Wz half
    f32x4 acc = {0.f, 0.f, 0.f, 0.f};
    #pragma unroll
    for (int q = 0; q < 8; ++q){
      bf16x8 bfr = wz[(ct * 8 + q) * 64 + lane];
      acc = __builtin_amdgcn_mfma_f32_16x16x32_bf16(a[q], bfr, acc, 0, 0, 0);
    }
    int c = ct * 16 + col;
    float bb = bias[c];
    if (FINAL){
      #pragma unroll
      for (int r = 0; r < 4; ++r){
        int row = rowq + r;
        if (row < NNODE) outf[(size_t)row * 64 + c] = acc[r] + bb;
      }
    } else {
      float uc = u[c], vc = v[c];
      #pragma unroll
      for (int r = 0; r < 4; ++r){
        float h = fmaxf(acc[r] + bb, 0.f);
        alsp[r] = fmaf(h, uc, alsp[r]);
        aldp[r] = fmaf(h, vc, aldp[r]);
        int row = rowq + r;
        if (row < NNODE) Hout[(size_t)row * 128 + c] = f2bf(h);
      }
    }
  }

  if (!FINAL){
    #pragma unroll
    for (int m = 1; m < 16; m <<= 1){
      #pragma unroll
      for (int r = 0; r < 4; ++r){
        alsp[r] += __shfl_xor(alsp[r], m);
        aldp[r] += __shfl_xor(aldp[r], m);
      }
    }
    if (col == 0){
      #pragma unroll
      for (int r = 0; r < 4; ++r){
        int row = rowq + r;
        if (row < NNODE){ als[row] = alsp[r]; ald[row] = aldp[r]; }
      }
    }
  }
}

extern "C" void kernel_launch(void* const* d_in, const int* in_sizes, int n_in,
                              void* d_out, int out_size, void* d_ws, size_t ws_size,
                              hipStream_t stream){
  const float* x   = (const float*)d_in[0];
  const int*   ei  = (const int*)d_in[1];
  const float* w0s = (const float*)d_in[2];
  const float* w0d = (const float*)d_in[3];
  const float* a0s = (const float*)d_in[4];
  const float* a0d = (const float*)d_in[5];
  const float* bc0 = (const float*)d_in[6];
  const float* wl0 = (const float*)d_in[7];
  const float* bl0 = (const float*)d_in[8];
  const float* w1  = (const float*)d_in[9];
  const float* a1s = (const float*)d_in[10];
  const float* a1d = (const float*)d_in[11];
  const float* bc1 = (const float*)d_in[12];
  const float* wl1 = (const float*)d_in[13];
  const float* bl1 = (const float*)d_in[14];
  const float* w2  = (const float*)d_in[15];
  const float* a2s = (const float*)d_in[16];
  const float* a2d = (const float*)d_in[17];
  const float* bc2 = (const float*)d_in[18];
  const float* wl2 = (const float*)d_in[19];
  const float* bl2 = (const float*)d_in[20];
  const float* wh  = (const float*)d_in[21];
  const float* bh  = (const float*)d_in[22];
  float* out = (float*)d_out;

  unsigned int* Xb = (unsigned int*)d_ws;                        // [N,128] bf16
  unsigned int* Ha = Xb + (size_t)NNODE * 64;                    // [N,128] bf16
  unsigned int* Hb = Ha + (size_t)NNODE * 64;                    // [N,128] bf16
  unsigned int* Mb = Hb + (size_t)NNODE * 64;                    // [N,128] bf16
  float* alsA = (float*)(Mb + (size_t)NNODE * 64);
  float* aldA = alsA + NNODE;
  float* alsB = aldA + NNODE;
  float* aldB = alsB + NNODE;
  float* uv   = aldB + NNODE;                // 6*128
  float* bf1  = uv + 6 * 128;                // 128
  float* bf2  = bf1 + 128;                   // 128
  float* bf3  = bf2 + 128;                   // 64
  unsigned short* Wz1 = (unsigned short*)(bf3 + 64);             // 256*128
  unsigned short* Wz2 = Wz1 + 256 * 128;                         // 256*128
  unsigned short* Wz3 = Wz2 + 256 * 128;                         // 256*64
  int*   rp    = (int*)(Wz3 + 256 * 64);     // NNODE+1
  int*   cnt   = rp + (NNODE + 1);           // NBUCK*NB1
  int*   cbase = cnt + NBUCK * NB1;          // NBUCK*NB1
  int*   btot  = cbase + NBUCK * NB1;        // NBUCK (unused, layout keep)
  int*   gbase = btot + NBUCK;               // NBUCK+1
  unsigned int* packed = (unsigned int*)(gbase + (NBUCK + 1));   // NEDGE
  unsigned short* es   = (unsigned short*)(packed + NEDGE);      // NEDGE

  dim3 b(256);
  dim3 b2(512);
  dim3 gn(GN);

  // ---- setup: bhist2 + weight swizzles + matvecs + x->bf16 (one launch) ----
  setup_k<<<SB_TOT, b, 0, stream>>>(ei, x,
      w0s, a0s, w0d, a0d, bc0, wl0, bl0,
      w1, a1s, a1d, bc1, wl1, bl1,
      w2, a2s, a2d, bc2, wl2, bl2, wh, bh,
      cnt, Wz1, Wz2, Wz3, bf3, uv, bf1, bf2, Xb);

  // ---- CSR: (row scans | gbase | layer-0 logits) + scatter + build ----
  scanx_k<<<SCX, b, 0, stream>>>(cnt, cbase, gbase, rp, x, uv, alsA, aldA);
  scat2_k<<<NB1, b, 0, stream>>>(ei, gbase, cbase, packed);
  build_k<<<NBUCK, b2, 0, stream>>>(gbase, packed, rp, es);

  // ---- layer 0: gather x -> M0; h1 = relu([M0|x]@Wf1 + bf1); logits1 -> B ----
  gat_k<<<gn, b, 0, stream>>>(rp, es, alsA, aldA, Xb, Mb);
  mfma_k<0><<<GBLK, b2, 0, stream>>>(Mb, Xb, Wz1, bf1, uv + 2 * 128, uv + 3 * 128,
                                     (unsigned short*)Ha, nullptr, alsB, aldB);

  // ---- layer 1 ----
  gat_k<<<gn, b, 0, stream>>>(rp, es, alsB, aldB, Ha, Mb);
  mfma_k<0><<<GBLK, b2, 0, stream>>>(Mb, Ha, Wz2, bf2, uv + 4 * 128, uv + 5 * 128,
                                     (unsigned short*)Hb, nullptr, alsA, aldA);

  // ---- layer 2 + head ----
  gat_k<<<gn, b, 0, stream>>>(rp, es, alsA, aldA, Hb, Mb);
  mfma_k<1><<<GBLK, b2, 0, stream>>>(Mb, Hb, Wz3, bf3, nullptr, nullptr,
                                     nullptr, out, nullptr, nullptr);
}

// Round 11
// 276.450 us; speedup vs baseline: 1.3049x; 1.3049x over previous
//
#include <hip/hip_runtime.h>

#define NNODE 50000
#define NEDGE 800000
#define DIM   128
#define NEG   0.2f
#define NBUCK 196
#define EPB1  2048
#define NB1   391
#define GBLK  391          // ceil(NNODE/128) for 512-thread mfma_k
#define GN    12500        // ceil(NNODE/4) node-blocks (4 waves of 1 node)
#define SB_PA (NB1)        // setup_k block ranges
#define SB_PH (SB_PA + 32)
#define SB_MV (SB_PH + 65) // prepH: 64 compute blocks + 1 bf3 block
#define SB_CV (SB_MV + 193)
#define SB_TOT (SB_CV + GN)
#define SCX   (NBUCK + 1 + GN)  // scanx_k: 196 scans + gbase + 12500 dual

typedef __attribute__((ext_vector_type(8))) short bf16x8;
typedef __attribute__((ext_vector_type(4))) float f32x4;

__device__ __forceinline__ float wmax(float v){
  #pragma unroll
  for (int m = 32; m > 0; m >>= 1) v = fmaxf(v, __shfl_xor(v, m));
  return v;
}
__device__ __forceinline__ float wsum(float v){
  #pragma unroll
  for (int m = 32; m > 0; m >>= 1) v += __shfl_xor(v, m);
  return v;
}
__device__ __forceinline__ unsigned short f2bf(float f){
  unsigned int x = __float_as_uint(f);
  return (unsigned short)((x + 0x7fffu + ((x >> 16) & 1u)) >> 16);
}
__device__ __forceinline__ float bflo(unsigned u){ return __uint_as_float(u << 16); }
__device__ __forceinline__ float bfhi(unsigned u){ return __uint_as_float(u & 0xffff0000u); }

// ---- setup_k: bhist2 | prepA | prepH | mv6 | cvt (independent, one launch) ----
__global__ __launch_bounds__(256) void setup_k(
    const int* __restrict__ ei,
    const float* __restrict__ x,
    const float* __restrict__ w0s, const float* __restrict__ a0s,
    const float* __restrict__ w0d, const float* __restrict__ a0d,
    const float* __restrict__ bc0, const float* __restrict__ wl0,
    const float* __restrict__ bl0,
    const float* __restrict__ w1,  const float* __restrict__ a1s,
    const float* __restrict__ a1d, const float* __restrict__ bc1,
    const float* __restrict__ wl1, const float* __restrict__ bl1,
    const float* __restrict__ w2,  const float* __restrict__ a2s,
    const float* __restrict__ a2d, const float* __restrict__ bc2,
    const float* __restrict__ wl2, const float* __restrict__ bl2,
    const float* __restrict__ wh,  const float* __restrict__ bh,
    int* __restrict__ cnt,
    unsigned short* __restrict__ Wz1, unsigned short* __restrict__ Wz2,
    unsigned short* __restrict__ Wz3, float* __restrict__ bf3,
    float* __restrict__ uv, float* __restrict__ bf1, float* __restrict__ bf2,
    unsigned int* __restrict__ Xb){
  int bid = blockIdx.x;

  if (bid < NB1){                       // ---- bhist2 ----
    __shared__ int h[NBUCK];
    const int* dst = ei + NEDGE;
    for (int i = threadIdx.x; i < NBUCK; i += 256) h[i] = 0;
    __syncthreads();
    int e0 = bid * EPB1 + threadIdx.x;
    #pragma unroll
    for (int i = 0; i < 8; ++i){
      int e = e0 + i * 256;
      if (e < NEDGE) atomicAdd(&h[dst[e] >> 8], 1);
    }
    __syncthreads();
    for (int i = threadIdx.x; i < NBUCK; i += 256)
      cnt[i * NB1 + bid] = h[i];
    return;
  }
  if (bid < SB_PH){                     // ---- prepA ----
    int g = (bid - SB_PA) * 256 + threadIdx.x;   // 0..8191
    int layer = g >> 12;
    int rem = g & 4095;
    int ct = rem >> 9, q = (rem >> 6) & 7, lane = rem & 63;
    int quad = lane >> 4;
    int c = ct * 16 + (lane & 15);
    const float* wA = layer ? w1 : w0s;
    const float* wB = layer ? wl1 : wl0;
    unsigned short* dst = (layer ? Wz2 : Wz1) + ((size_t)(ct * 8 + q) * 64 + lane) * 8;
    #pragma unroll
    for (int j = 0; j < 8; ++j){
      int k = q * 32 + quad * 8 + j;
      float v = (k < 128) ? wA[k * 128 + c] : wB[(k - 128) * 128 + c];
      dst[j] = f2bf(v);
    }
    return;
  }
  if (bid < SB_MV){                     // ---- prepH: one output per thread ----
    int pb = bid - SB_PH;
    if (pb == 64){
      int c = threadIdx.x;
      if (c < 64){
        float s = bh[c];
        for (int t = 0; t < 128; ++t) s += (bc2[t] + bl2[t]) * wh[t * 64 + c];
        bf3[c] = s;
      }
      return;
    }
    int g = pb * 256 + threadIdx.x;     // 0..16383
    int k = g >> 6, c = g & 63;
    const float* src = (k < 128) ? (w2 + k * 128) : (wl2 + (k - 128) * 128);
    float s = 0.f;
    for (int t = 0; t < 128; ++t) s += src[t] * wh[t * 64 + c];
    int ct = c >> 4, q = k >> 5, quad = (k >> 3) & 3, j = k & 7;
    int ln = quad * 16 + (c & 15);
    Wz3[((size_t)(ct * 8 + q) * 64 + ln) * 8 + j] = f2bf(s);
    return;
  }
  if (bid < SB_CV){                     // ---- mv6 + fused biases ----
    int mb = bid - SB_MV;
    if (mb == 192){
      int t = threadIdx.x;
      if (t < 128) bf1[t] = bc0[t] + bl0[t];
      else bf2[t - 128] = bc1[t - 128] + bl1[t - 128];
      return;
    }
    int lane = threadIdx.x & 63;
    int idx = mb * 4 + (threadIdx.x >> 6);   // 0..767
    int grp = idx >> 7, r = idx & 127;
    const float* W; const float* a;
    switch (grp){
      case 0: W = w0s; a = a0s; break;
      case 1: W = w0d; a = a0d; break;
      case 2: W = w1;  a = a1s; break;
      case 3: W = w1;  a = a1d; break;
      case 4: W = w2;  a = a2s; break;
      default: W = w2; a = a2d; break;
    }
    float2 w = ((const float2*)(W + r * DIM))[lane];
    float2 av = ((const float2*)a)[lane];
    float s = wsum(w.x * av.x + w.y * av.y);
    if (lane == 0) uv[grp * 128 + r] = s;
    return;
  }
  {                                     // ---- cvt: x -> bf16 row-major ----
    int lane = threadIdx.x & 63;
    int n = (bid - SB_CV) * 4 + (threadIdx.x >> 6);
    if (n >= NNODE) return;
    float2 xv = ((const float2*)(x + (size_t)n * DIM))[lane];
    Xb[(size_t)n * 64 + lane] = (unsigned)f2bf(xv.x) | ((unsigned)f2bf(xv.y) << 16);
  }
}

// ---- scanx_k: per-bucket row scans | gbase | dual ----
// gbase branch: r9's per-thread serial-row version. Each thread walks ITS OWN
// row sequentially -> 31/32 of loads L1-hit (~6us). r10's wave-per-bucket
// "coalesced" rewrite was latency-serial (divergent trip count -> no unroll,
// one L2/L3 round-trip per iteration) and became an 80us single-block tail
// (measured: scanx 103us, occupancy 6%).
__global__ __launch_bounds__(256) void scanx_k(const int* __restrict__ cnt,
                                               int* __restrict__ cbase,
                                               int* __restrict__ gbase,
                                               int* __restrict__ rp,
                                               const float* __restrict__ X,
                                               const float* __restrict__ uv,
                                               float* __restrict__ als,
                                               float* __restrict__ ald){
  int bid = blockIdx.x, t = threadIdx.x;
  if (bid < NBUCK){                     // ---- row scan for bucket bid ----
    __shared__ int sd[256];
    const int* row = cnt + (size_t)bid * NB1;
    int i0 = t * 2, i1 = t * 2 + 1;
    int v0 = (i0 < NB1) ? row[i0] : 0;
    int v1 = (i1 < NB1) ? row[i1] : 0;
    int s = v0 + v1;
    sd[t] = s; __syncthreads();
    #pragma unroll
    for (int off = 1; off < 256; off <<= 1){
      int u = (t >= off) ? sd[t - off] : 0;
      __syncthreads();
      sd[t] += u;
      __syncthreads();
    }
    int ex = sd[t] - s;
    if (i0 < NB1) cbase[(size_t)bid * NB1 + i0] = ex;
    if (i1 < NB1) cbase[(size_t)bid * NB1 + i1] = ex + v0;
    return;
  }
  if (bid == NBUCK){                    // ---- gbase: totals + scan ----
    __shared__ int sd[256];
    int tot = 0;
    if (t < NBUCK){
      const int* row = cnt + (size_t)t * NB1;
      for (int j = 0; j < NB1; ++j) tot += row[j];
    }
    sd[t] = tot; __syncthreads();
    #pragma unroll
    for (int off = 1; off < 256; off <<= 1){
      int u = (t >= off) ? sd[t - off] : 0;
      __syncthreads();
      sd[t] += u;
      __syncthreads();
    }
    if (t < NBUCK) gbase[t] = sd[t] - tot;
    if (t == NBUCK - 1) gbase[NBUCK] = sd[t];
    if (t == 0) rp[NNODE] = NEDGE;
    return;
  }
  {                                     // ---- layer-0 logits: x@u, x@v ----
    int lane = t & 63;
    int n = (bid - NBUCK - 1) * 4 + (t >> 6);
    if (n >= NNODE) return;
    float2 xv = ((const float2*)(X + (size_t)n * DIM))[lane];
    float2 uu = ((const float2*)uv)[lane];
    float2 vv = ((const float2*)(uv + 128))[lane];
    float s1 = wsum(xv.x * uu.x + xv.y * uu.y);
    float s2 = wsum(xv.x * vv.x + xv.y * vv.y);
    if (lane == 0){ als[n] = s1; ald[n] = s2; }
  }
}

__global__ __launch_bounds__(256) void scat2_k(const int* __restrict__ ei,
                                               const int* __restrict__ gbase,
                                               const int* __restrict__ cbase,
                                               unsigned int* __restrict__ packed){
  __shared__ int lcur[NBUCK];
  for (int i = threadIdx.x; i < NBUCK; i += 256) lcur[i] = 0;
  __syncthreads();
  int e0 = blockIdx.x * EPB1 + threadIdx.x;
  #pragma unroll
  for (int i = 0; i < 8; ++i){
    int e = e0 + i * 256;
    if (e < NEDGE){
      int s = ei[e], d = ei[NEDGE + e];
      int b = d >> 8;
      int r = atomicAdd(&lcur[b], 1);
      int pos = gbase[b] + cbase[(size_t)b * NB1 + blockIdx.x] + r;
      packed[pos] = ((unsigned)d << 16) | (unsigned)s;
    }
  }
}

// 512 threads: doubles resident waves vs 196x256 (784 waves on 1024 SIMDs).
__global__ __launch_bounds__(512) void build_k(const int* __restrict__ gbase,
                                               const unsigned int* __restrict__ packed,
                                               int* __restrict__ rp,
                                               unsigned short* __restrict__ es){
  __shared__ int h[256], sd[256], cur[256];
  int b = blockIdx.x, t = threadIdx.x;
  int s0 = gbase[b], s1 = gbase[b + 1];
  if (t < 256) h[t] = 0;
  __syncthreads();
  for (int i = s0 + t; i < s1; i += 512)
    atomicAdd(&h[(packed[i] >> 16) & 255], 1);
  __syncthreads();
  int v = (t < 256) ? h[t] : 0;
  if (t < 256) sd[t] = v;
  __syncthreads();
  #pragma unroll
  for (int off = 1; off < 256; off <<= 1){
    int u = (t >= off && t < 256) ? sd[t - off] : 0;
    __syncthreads();
    if (t < 256) sd[t] += u;
    __syncthreads();
  }
  if (t < 256){
    int ex = sd[t] - v;
    cur[t] = ex;
    int d = b * 256 + t;
    if (d < NNODE) rp[d] = s0 + ex;
  }
  __syncthreads();
  for (int i = s0 + t; i < s1; i += 512){
    unsigned int p = packed[i];
    int ld = (p >> 16) & 255;
    int pos = atomicAdd(&cur[ld], 1);
    es[s0 + pos] = (unsigned short)(p & 0xffffu);
  }
}

// ---------------- GAT: Mb[n] = softmax-weighted sum of Hg rows (bf16) ----------------
__global__ __launch_bounds__(256) void gat_k(const int* __restrict__ rp,
                                             const unsigned short* __restrict__ es,
                                             const float* __restrict__ als,
                                             const float* __restrict__ ald,
                                             const unsigned int* __restrict__ A,
                                             unsigned int* __restrict__ Mb){
  int lane = threadIdx.x & 63;
  int n = blockIdx.x * 4 + (threadIdx.x >> 6);
  if (n >= NNODE) return;
  int start = rp[n], end = rp[n + 1];
  int deg = end - start;
  float ad = ald[n];
  int half = lane >> 4, sub = lane & 15;
  const uint4* A4 = (const uint4*)A;

  if (deg <= 32){
    int s = (lane < deg) ? (int)es[start + lane] : 0;
    float alv = (lane < deg) ? als[s] : 0.f;   // issue scattered 4B load early

    int s0 = __shfl(s, half),      s1 = __shfl(s, 4 + half);
    int s2 = __shfl(s, 8 + half),  s3 = __shfl(s, 12 + half);
    uint4 p0 = A4[(size_t)s0 * 16 + sub];
    uint4 p1 = A4[(size_t)s1 * 16 + sub];
    uint4 p2 = A4[(size_t)s2 * 16 + sub];
    uint4 p3 = A4[(size_t)s3 * 16 + sub];
    uint4 p4, p5, p6, p7;
    bool big = deg > 16;
    if (big){
      int s4 = __shfl(s, 16 + half), s5 = __shfl(s, 20 + half);
      int s6 = __shfl(s, 24 + half), s7 = __shfl(s, 28 + half);
      p4 = A4[(size_t)s4 * 16 + sub];
      p5 = A4[(size_t)s5 * 16 + sub];
      p6 = A4[(size_t)s6 * 16 + sub];
      p7 = A4[(size_t)s7 * 16 + sub];
    }

    float z = -3.0e38f;
    if (lane < deg){
      float t = alv + ad;
      z = t > 0.f ? t : NEG * t;
    }
    float m = wmax(z);
    float e = (lane < deg) ? __expf(z - m) : 0.f;
    float denom = wsum(e);
    float rinv = (deg > 0) ? 1.f / denom : 0.f;

    float w0 = __shfl(e, half),      w1 = __shfl(e, 4 + half);
    float w2 = __shfl(e, 8 + half),  w3 = __shfl(e, 12 + half);
    float a0=0.f,a1=0.f,a2=0.f,a3=0.f,a4=0.f,a5=0.f,a6=0.f,a7=0.f;
    a0 = fmaf(w0, bflo(p0.x), a0); a1 = fmaf(w0, bfhi(p0.x), a1);
    a2 = fmaf(w0, bflo(p0.y), a2); a3 = fmaf(w0, bfhi(p0.y), a3);
    a4 = fmaf(w0, bflo(p0.z), a4); a5 = fmaf(w0, bfhi(p0.z), a5);
    a6 = fmaf(w0, bflo(p0.w), a6); a7 = fmaf(w0, bfhi(p0.w), a7);
    a0 = fmaf(w1, bflo(p1.x), a0); a1 = fmaf(w1, bfhi(p1.x), a1);
    a2 = fmaf(w1, bflo(p1.y), a2); a3 = fmaf(w1, bfhi(p1.y), a3);
    a4 = fmaf(w1, bflo(p1.z), a4); a5 = fmaf(w1, bfhi(p1.z), a5);
    a6 = fmaf(w1, bflo(p1.w), a6); a7 = fmaf(w1, bfhi(p1.w), a7);
    a0 = fmaf(w2, bflo(p2.x), a0); a1 = fmaf(w2, bfhi(p2.x), a1);
    a2 = fmaf(w2, bflo(p2.y), a2); a3 = fmaf(w2, bfhi(p2.y), a3);
    a4 = fmaf(w2, bflo(p2.z), a4); a5 = fmaf(w2, bfhi(p2.z), a5);
    a6 = fmaf(w2, bflo(p2.w), a6); a7 = fmaf(w2, bfhi(p2.w), a7);
    a0 = fmaf(w3, bflo(p3.x), a0); a1 = fmaf(w3, bfhi(p3.x), a1);
    a2 = fmaf(w3, bflo(p3.y), a2); a3 = fmaf(w3, bfhi(p3.y), a3);
    a4 = fmaf(w3, bflo(p3.z), a4); a5 = fmaf(w3, bfhi(p3.z), a5);
    a6 = fmaf(w3, bflo(p3.w), a6); a7 = fmaf(w3, bfhi(p3.w), a7);
    if (big){
      float w4 = __shfl(e, 16 + half), w5 = __shfl(e, 20 + half);
      float w6 = __shfl(e, 24 + half), w7 = __shfl(e, 28 + half);
      a0 = fmaf(w4, bflo(p4.x), a0); a1 = fmaf(w4, bfhi(p4.x), a1);
      a2 = fmaf(w4, bflo(p4.y), a2); a3 = fmaf(w4, bfhi(p4.y), a3);
      a4 = fmaf(w4, bflo(p4.z), a4); a5 = fmaf(w4, bfhi(p4.z), a5);
      a6 = fmaf(w4, bflo(p4.w), a6); a7 = fmaf(w4, bfhi(p4.w), a7);
      a0 = fmaf(w5, bflo(p5.x), a0); a1 = fmaf(w5, bfhi(p5.x), a1);
      a2 = fmaf(w5, bflo(p5.y), a2); a3 = fmaf(w5, bfhi(p5.y), a3);
      a4 = fmaf(w5, bflo(p5.z), a4); a5 = fmaf(w5, bfhi(p5.z), a5);
      a6 = fmaf(w5, bflo(p5.w), a6); a7 = fmaf(w5, bfhi(p5.w), a7);
      a0 = fmaf(w6, bflo(p6.x), a0); a1 = fmaf(w6, bfhi(p6.x), a1);
      a2 = fmaf(w6, bflo(p6.y), a2); a3 = fmaf(w6, bfhi(p6.y), a3);
      a4 = fmaf(w6, bflo(p6.z), a4); a5 = fmaf(w6, bfhi(p6.z), a5);
      a6 = fmaf(w6, bflo(p6.w), a6); a7 = fmaf(w6, bfhi(p6.w), a7);
      a0 = fmaf(w7, bflo(p7.x), a0); a1 = fmaf(w7, bfhi(p7.x), a1);
      a2 = fmaf(w7, bflo(p7.y), a2); a3 = fmaf(w7, bfhi(p7.y), a3);
      a4 = fmaf(w7, bflo(p7.z), a4); a5 = fmaf(w7, bfhi(p7.z), a5);
      a6 = fmaf(w7, bflo(p7.w), a6); a7 = fmaf(w7, bfhi(p7.w), a7);
    }
    #define RED(vv) vv += __shfl_xor(vv, 16); vv += __shfl_xor(vv, 32);
    RED(a0) RED(a1) RED(a2) RED(a3) RED(a4) RED(a5) RED(a6) RED(a7)
    #undef RED
    if (half == 0){
      uint4 o;
      o.x = (unsigned)f2bf(a0 * rinv) | ((unsigned)f2bf(a1 * rinv) << 16);
      o.y = (unsigned)f2bf(a2 * rinv) | ((unsigned)f2bf(a3 * rinv) << 16);
      o.z = (unsigned)f2bf(a4 * rinv) | ((unsigned)f2bf(a5 * rinv) << 16);
      o.w = (unsigned)f2bf(a6 * rinv) | ((unsigned)f2bf(a7 * rinv) << 16);
      ((uint4*)(Mb + (size_t)n * 64))[sub] = o;
    }
    return;
  }

  if (deg <= 64){
    int s = 0; float z = -3.0e38f;
    if (lane < deg){
      s = es[start + lane];
      float t = als[s] + ad;
      z = t > 0.f ? t : NEG * t;
    }
    float m = wmax(z);
    float e = (lane < deg) ? __expf(z - m) : 0.f;
    float denom = wsum(e);
    float rinv = (deg > 0) ? 1.f / denom : 0.f;

    float a0=0.f,a1=0.f,a2=0.f,a3=0.f,a4=0.f,a5=0.f,a6=0.f,a7=0.f;
    int dq = (deg + 7) & ~7;
    for (int j = 0; j < dq; j += 8){
      int   sA = __shfl(s, j + half);
      int   sB = __shfl(s, j + 4 + half);
      float wA = __shfl(e, j + half);
      float wB = __shfl(e, j + 4 + half);
      uint4 pA = A4[(size_t)sA * 16 + sub];
      uint4 pB = A4[(size_t)sB * 16 + sub];
      a0 = fmaf(wA, bflo(pA.x), a0); a1 = fmaf(wA, bfhi(pA.x), a1);
      a2 = fmaf(wA, bflo(pA.y), a2); a3 = fmaf(wA, bfhi(pA.y), a3);
      a4 = fmaf(wA, bflo(pA.z), a4); a5 = fmaf(wA, bfhi(pA.z), a5);
      a6 = fmaf(wA, bflo(pA.w), a6); a7 = fmaf(wA, bfhi(pA.w), a7);
      a0 = fmaf(wB, bflo(pB.x), a0); a1 = fmaf(wB, bfhi(pB.x), a1);
      a2 = fmaf(wB, bflo(pB.y), a2); a3 = fmaf(wB, bfhi(pB.y), a3);
      a4 = fmaf(wB, bflo(pB.z), a4); a5 = fmaf(wB, bfhi(pB.z), a5);
      a6 = fmaf(wB, bflo(pB.w), a6); a7 = fmaf(wB, bfhi(pB.w), a7);
    }
    #define RED(vv) vv += __shfl_xor(vv, 16); vv += __shfl_xor(vv, 32);
    RED(a0) RED(a1) RED(a2) RED(a3) RED(a4) RED(a5) RED(a6) RED(a7)
    #undef RED
    if (half == 0){
      uint4 o;
      o.x = (unsigned)f2bf(a0 * rinv) | ((unsigned)f2bf(a1 * rinv) << 16);
      o.y = (unsigned)f2bf(a2 * rinv) | ((unsigned)f2bf(a3 * rinv) << 16);
      o.z = (unsigned)f2bf(a4 * rinv) | ((unsigned)f2bf(a5 * rinv) << 16);
      o.w = (unsigned)f2bf(a6 * rinv) | ((unsigned)f2bf(a7 * rinv) << 16);
      ((uint4*)(Mb + (size_t)n * 64))[sub] = o;
    }
  } else {
    float2 acc = make_float2(0.f, 0.f);
    float mloc = -3.0e38f;
    for (int i = start + lane; i < end; i += 64){
      int s = es[i];
      float zz = als[s] + ad;
      zz = zz > 0.f ? zz : NEG * zz;
      mloc = fmaxf(mloc, zz);
    }
    float m = wmax(mloc);
    float dloc = 0.f;
    for (int i = start + lane; i < end; i += 64){
      int s = es[i];
      float zz = als[s] + ad;
      zz = zz > 0.f ? zz : NEG * zz;
      dloc += __expf(zz - m);
    }
    float rinv = 1.f / wsum(dloc);
    for (int i = start; i < end; ++i){
      int s = es[i];
      float zz = als[s] + ad;
      zz = zz > 0.f ? zz : NEG * zz;
      float w = __expf(zz - m);
      unsigned p = A[(size_t)s * 64 + lane];
      acc.x = fmaf(w, bflo(p), acc.x);
      acc.y = fmaf(w, bfhi(p), acc.y);
    }
    Mb[(size_t)n * 64 + lane] =
        (unsigned)f2bf(acc.x * rinv) | ((unsigned)f2bf(acc.y * rinv) << 16);
  }
}

// ------- K=256 fused MFMA: out = [Mb | Hin] @ Wz + bias ------------------
// 512 threads (8 waves, 128 rows/block): 8 waves share each 32KB Wz half
// through L1 (sync at ct==4 keeps them in the same window).
template<int FINAL>
__global__ __launch_bounds__(512) void mfma_k(const unsigned int* __restrict__ Mb,
                                              const unsigned int* __restrict__ Hin,
                                              const unsigned short* __restrict__ Wz,
                                              const float* __restrict__ bias,
                                              const float* __restrict__ u,
                                              const float* __restrict__ v,
                                              unsigned short* __restrict__ Hout,
                                              float* __restrict__ outf,
                                              float* __restrict__ als,
                                              float* __restrict__ ald){
  int lane = threadIdx.x & 63;
  int wid  = threadIdx.x >> 6;          // 0..7
  int r0   = blockIdx.x * 128 + wid * 16;
  int quad = lane >> 4;
  int col  = lane & 15;

  int rA = r0 + col; if (rA > NNODE - 1) rA = NNODE - 1;
  const bf16x8* mrow = (const bf16x8*)(Mb + (size_t)rA * 64);
  const bf16x8* hrow = (const bf16x8*)(Hin + (size_t)rA * 64);
  bf16x8 a[8];
  #pragma unroll
  for (int q = 0; q < 4; ++q){
    a[q]     = mrow[q * 4 + quad];
    a[q + 4] = hrow[q * 4 + quad];
  }

  const bf16x8* wz = (const bf16x8*)Wz;
  int rowq = r0 + quad * 4;
  float alsp[4] = {0.f, 0.f, 0.f, 0.f};
  float aldp[4] = {0.f, 0.f, 0.f, 0.f};
  const int NCT = FINAL ? 4 : 8;

  #pragma unroll
  for (int ct = 0; ct < NCT; ++ct){
    if (!FINAL && ct == 4) __syncthreads();   // keep waves in same 32KB Wz half
    f32x4 acc = {0.f, 0.f, 0.f, 0.f};
    #pragma unroll
    for (int q = 0; q < 8; ++q){
      bf16x8 bfr = wz[(ct * 8 + q) * 64 + lane];
      acc = __builtin_amdgcn_mfma_f32_16x16x32_bf16(a[q], bfr, acc, 0, 0, 0);
    }
    int c = ct * 16 + col;
    float bb = bias[c];
    if (FINAL){
      #pragma unroll
      for (int r = 0; r < 4; ++r){
        int row = rowq + r;
        if (row < NNODE) outf[(size_t)row * 64 + c] = acc[r] + bb;
      }
    } else {
      float uc = u[c], vc = v[c];
      #pragma unroll
      for (int r = 0; r < 4; ++r){
        float h = fmaxf(acc[r] + bb, 0.f);
        alsp[r] = fmaf(h, uc, alsp[r]);
        aldp[r] = fmaf(h, vc, aldp[r]);
        int row = rowq + r;
        if (row < NNODE) Hout[(size_t)row * 128 + c] = f2bf(h);
      }
    }
  }

  if (!FINAL){
    #pragma unroll
    for (int m = 1; m < 16; m <<= 1){
      #pragma unroll
      for (int r = 0; r < 4; ++r){
        alsp[r] += __shfl_xor(alsp[r], m);
        aldp[r] += __shfl_xor(aldp[r], m);
      }
    }
    if (col == 0){
      #pragma unroll
      for (int r = 0; r < 4; ++r){
        int row = rowq + r;
        if (row < NNODE){ als[row] = alsp[r]; ald[row] = aldp[r]; }
      }
    }
  }
}

extern "C" void kernel_launch(void* const* d_in, const int* in_sizes, int n_in,
                              void* d_out, int out_size, void* d_ws, size_t ws_size,
                              hipStream_t stream){
  const float* x   = (const float*)d_in[0];
  const int*   ei  = (const int*)d_in[1];
  const float* w0s = (const float*)d_in[2];
  const float* w0d = (const float*)d_in[3];
  const float* a0s = (const float*)d_in[4];
  const float* a0d = (const float*)d_in[5];
  const float* bc0 = (const float*)d_in[6];
  const float* wl0 = (const float*)d_in[7];
  const float* bl0 = (const float*)d_in[8];
  const float* w1  = (const float*)d_in[9];
  const float* a1s = (const float*)d_in[10];
  const float* a1d = (const float*)d_in[11];
  const float* bc1 = (const float*)d_in[12];
  const float* wl1 = (const float*)d_in[13];
  const float* bl1 = (const float*)d_in[14];
  const float* w2  = (const float*)d_in[15];
  const float* a2s = (const float*)d_in[16];
  const float* a2d = (const float*)d_in[17];
  const float* bc2 = (const float*)d_in[18];
  const float* wl2 = (const float*)d_in[19];
  const float* bl2 = (const float*)d_in[20];
  const float* wh  = (const float*)d_in[21];
  const float* bh  = (const float*)d_in[22];
  float* out = (float*)d_out;

  unsigned int* Xb = (unsigned int*)d_ws;                        // [N,128] bf16
  unsigned int* Ha = Xb + (size_t)NNODE * 64;                    // [N,128] bf16
  unsigned int* Hb = Ha + (size_t)NNODE * 64;                    // [N,128] bf16
  unsigned int* Mb = Hb + (size_t)NNODE * 64;                    // [N,128] bf16
  float* alsA = (float*)(Mb + (size_t)NNODE * 64);
  float* aldA = alsA + NNODE;
  float* alsB = aldA + NNODE;
  float* aldB = alsB + NNODE;
  float* uv   = aldB + NNODE;                // 6*128
  float* bf1  = uv + 6 * 128;                // 128
  float* bf2  = bf1 + 128;                   // 128
  float* bf3  = bf2 + 128;                   // 64
  unsigned short* Wz1 = (unsigned short*)(bf3 + 64);             // 256*128
  unsigned short* Wz2 = Wz1 + 256 * 128;                         // 256*128
  unsigned short* Wz3 = Wz2 + 256 * 128;                         // 256*64
  int*   rp    = (int*)(Wz3 + 256 * 64);     // NNODE+1
  int*   cnt   = rp + (NNODE + 1);           // NBUCK*NB1
  int*   cbase = cnt + NBUCK * NB1;          // NBUCK*NB1
  int*   btot  = cbase + NBUCK * NB1;        // NBUCK (unused, layout keep)
  int*   gbase = btot + NBUCK;               // NBUCK+1
  unsigned int* packed = (unsigned int*)(gbase + (NBUCK + 1));   // NEDGE
  unsigned short* es   = (unsigned short*)(packed + NEDGE);      // NEDGE

  dim3 b(256);
  dim3 b2(512);
  dim3 gn(GN);

  // ---- setup: bhist2 + weight swizzles + matvecs + x->bf16 (one launch) ----
  setup_k<<<SB_TOT, b, 0, stream>>>(ei, x,
      w0s, a0s, w0d, a0d, bc0, wl0, bl0,
      w1, a1s, a1d, bc1, wl1, bl1,
      w2, a2s, a2d, bc2, wl2, bl2, wh, bh,
      cnt, Wz1, Wz2, Wz3, bf3, uv, bf1, bf2, Xb);

  // ---- CSR: (row scans | gbase | layer-0 logits) + scatter + build ----
  scanx_k<<<SCX, b, 0, stream>>>(cnt, cbase, gbase, rp, x, uv, alsA, aldA);
  scat2_k<<<NB1, b, 0, stream>>>(ei, gbase, cbase, packed);
  build_k<<<NBUCK, b2, 0, stream>>>(gbase, packed, rp, es);

  // ---- layer 0: gather x -> M0; h1 = relu([M0|x]@Wf1 + bf1); logits1 -> B ----
  gat_k<<<gn, b, 0, stream>>>(rp, es, alsA, aldA, Xb, Mb);
  mfma_k<0><<<GBLK, b2, 0, stream>>>(Mb, Xb, Wz1, bf1, uv + 2 * 128, uv + 3 * 128,
                                     (unsigned short*)Ha, nullptr, alsB, aldB);

  // ---- layer 1 ----
  gat_k<<<gn, b, 0, stream>>>(rp, es, alsB, aldB, Ha, Mb);
  mfma_k<0><<<GBLK, b2, 0, stream>>>(Mb, Ha, Wz2, bf2, uv + 4 * 128, uv + 5 * 128,
                                     (unsigned short*)Hb, nullptr, alsA, aldA);

  // ---- layer 2 + head ----
  gat_k<<<gn, b, 0, stream>>>(rp, es, alsA, aldA, Hb, Mb);
  mfma_k<1><<<GBLK, b2, 0, stream>>>(Mb, Hb, Wz3, bf3, nullptr, nullptr,
                                     nullptr, out, nullptr, nullptr);
}